// Round 1
// baseline (1173.894 us; speedup 1.0000x reference)
//
#include <hip/hip_runtime.h>

#define NROWS 32768   // B*T = 16*2048
#define DIM 256
#define KCODES 1024
#define NLEV 4

// ---------------- codebook squared norms (all levels) ----------------
__global__ __launch_bounds__(256) void k_bnorm(const float* __restrict__ cb,
                                               float* __restrict__ bv) {
  int r = blockIdx.x * blockDim.x + threadIdx.x;  // 0..4095
  if (r >= NLEV * KCODES) return;
  const float4* p = reinterpret_cast<const float4*>(cb + (size_t)r * DIM);
  float s0 = 0.f, s1 = 0.f, s2 = 0.f, s3 = 0.f;
  for (int g = 0; g < DIM / 4; ++g) {
    float4 v = p[g];
    s0 += v.x * v.x; s1 += v.y * v.y; s2 += v.z * v.z; s3 += v.w * v.w;
  }
  bv[r] = (s0 + s1) + (s2 + s3);
}

// ---------------- fused distance + argmin, one level ----------------
// block: 256 threads = 16 tx (codes) x 16 ty (rows); block tile 64 rows.
// Mimics reference f32 rounding: d = fl(fl(A + B_k) - 2*dot_k), first-index ties.
__global__ __launch_bounds__(256) void k_argmin(const float* __restrict__ resid,
                                                const float* __restrict__ cb,
                                                const float* __restrict__ bv,
                                                int* __restrict__ idx_out) {
  __shared__ __align__(16) float Rt[32][68];    // [d][row], pad 68 vs 64
  __shared__ __align__(16) float Ct[32][260];   // [d][code], pad 260 vs 256
  __shared__ float Asum[64];
  __shared__ float redm[64][16];
  __shared__ int   redi[64][16];

  const int tid = threadIdx.x;
  const int tx = tid & 15;
  const int ty = tid >> 4;
  const int row0 = blockIdx.x * 64;

  // --- per-row ||r||^2 (value only needs to be a valid f32 approx; a whole-ulp
  //     offset vs reference shifts all d_k uniformly -> argmin invariant) ---
  {
    int r = tid >> 2;     // 0..63
    int part = tid & 3;   // 0..3, 64 elems each
    const float4* p = reinterpret_cast<const float4*>(
        resid + (size_t)(row0 + r) * DIM + part * 64);
    float s0 = 0.f, s1 = 0.f, s2 = 0.f, s3 = 0.f;
    #pragma unroll
    for (int g = 0; g < 16; ++g) {
      float4 v = p[g];
      s0 += v.x * v.x; s1 += v.y * v.y; s2 += v.z * v.z; s3 += v.w * v.w;
    }
    redm[r][part] = (s0 + s1) + (s2 + s3);
  }
  __syncthreads();
  if (tid < 64)
    Asum[tid] = (redm[tid][0] + redm[tid][1]) + (redm[tid][2] + redm[tid][3]);
  __syncthreads();

  float rm[4] = {__builtin_inff(), __builtin_inff(), __builtin_inff(), __builtin_inff()};
  int   ri[4] = {0, 0, 0, 0};

  for (int n0 = 0; n0 < KCODES; n0 += 256) {
    float acc[4][16];
    #pragma unroll
    for (int i = 0; i < 4; ++i)
      #pragma unroll
      for (int j = 0; j < 16; ++j) acc[i][j] = 0.f;

    for (int d0 = 0; d0 < DIM; d0 += 32) {
      // stage R tile: 64 rows x 32 d, transposed into Rt[d][row]
      {
        int dd = (tid & 7) * 4;
        int rr = tid >> 3;  // 0..31
        #pragma unroll
        for (int pass = 0; pass < 2; ++pass) {
          float4 v = *reinterpret_cast<const float4*>(
              resid + (size_t)(row0 + rr) * DIM + d0 + dd);
          Rt[dd + 0][rr] = v.x; Rt[dd + 1][rr] = v.y;
          Rt[dd + 2][rr] = v.z; Rt[dd + 3][rr] = v.w;
          rr += 32;
        }
      }
      // stage C tile: 256 codes x 32 d, transposed into Ct[d][code]
      {
        int dd = (tid & 7) * 4;
        int cc = tid >> 3;  // 0..31
        #pragma unroll
        for (int pass = 0; pass < 8; ++pass) {
          float4 v = *reinterpret_cast<const float4*>(
              cb + (size_t)(n0 + cc) * DIM + d0 + dd);
          Ct[dd + 0][cc] = v.x; Ct[dd + 1][cc] = v.y;
          Ct[dd + 2][cc] = v.z; Ct[dd + 3][cc] = v.w;
          cc += 32;
        }
      }
      __syncthreads();
      #pragma unroll 4
      for (int d = 0; d < 32; ++d) {
        float4 rv = *reinterpret_cast<const float4*>(&Rt[d][ty * 4]);
        float4 c0 = *reinterpret_cast<const float4*>(&Ct[d][4 * tx]);
        float4 c1 = *reinterpret_cast<const float4*>(&Ct[d][64 + 4 * tx]);
        float4 c2 = *reinterpret_cast<const float4*>(&Ct[d][128 + 4 * tx]);
        float4 c3 = *reinterpret_cast<const float4*>(&Ct[d][192 + 4 * tx]);
        float rr4[4] = {rv.x, rv.y, rv.z, rv.w};
        float cc16[16] = {c0.x, c0.y, c0.z, c0.w, c1.x, c1.y, c1.z, c1.w,
                          c2.x, c2.y, c2.z, c2.w, c3.x, c3.y, c3.z, c3.w};
        #pragma unroll
        for (int i = 0; i < 4; ++i)
          #pragma unroll
          for (int j = 0; j < 16; ++j)
            acc[i][j] += rr4[i] * cc16[j];
      }
      __syncthreads();
    }
    // epilogue: form quantized distances, update running argmin in ascending
    // global code order (strict < keeps first occurrence, like jnp.argmin)
    #pragma unroll
    for (int i = 0; i < 4; ++i) {
      float a = Asum[ty * 4 + i];
      #pragma unroll
      for (int j = 0; j < 4; ++j) {
        #pragma unroll
        for (int q = 0; q < 4; ++q) {
          int c = n0 + 64 * j + 4 * tx + q;
          float t = a + bv[c];            // fl(A + B)
          float dd = t - 2.0f * acc[i][4 * j + q];  // 2*dot exact; one rounding
          if (dd < rm[i]) { rm[i] = dd; ri[i] = c; }
        }
      }
    }
  }

  // cross-thread (tx) reduce with (d, idx) lexicographic order
  #pragma unroll
  for (int i = 0; i < 4; ++i) {
    redm[ty * 4 + i][tx] = rm[i];
    redi[ty * 4 + i][tx] = ri[i];
  }
  __syncthreads();
  if (tid < 64) {
    float best = redm[tid][0];
    int bi = redi[tid][0];
    #pragma unroll
    for (int t = 1; t < 16; ++t) {
      float d = redm[tid][t];
      int ii = redi[tid][t];
      if (d < best || (d == best && ii < bi)) { best = d; bi = ii; }
    }
    idx_out[row0 + tid] = bi;
  }
}

// ---------------- residual update + quant accumulate + loss partials ----------------
// block: 256 threads, 8 rows/block, 8 f32 per thread
__global__ __launch_bounds__(256) void k_update(const float* __restrict__ rin,
                                                float* __restrict__ rout,
                                                const float* __restrict__ cb,
                                                const int* __restrict__ idx,
                                                float* __restrict__ tq,
                                                float* __restrict__ fidx,
                                                float* __restrict__ part,
                                                int lvl) {
  __shared__ float sred[256];
  const int tid = threadIdx.x;
  const int row = blockIdx.x * 8 + (tid >> 5);
  const int lane = tid & 31;
  const int id = idx[row];
  const size_t base = (size_t)row * DIM + lane * 8;

  const float4* rp = reinterpret_cast<const float4*>(rin + base);
  const float4* cp = reinterpret_cast<const float4*>(cb + (size_t)id * DIM + lane * 8);
  float4 r0 = rp[0], r1 = rp[1];
  float4 c0 = cp[0], c1 = cp[1];
  float4 n0, n1;
  n0.x = r0.x - c0.x; n0.y = r0.y - c0.y; n0.z = r0.z - c0.z; n0.w = r0.w - c0.w;
  n1.x = r1.x - c1.x; n1.y = r1.y - c1.y; n1.z = r1.z - c1.z; n1.w = r1.w - c1.w;
  float4* op = reinterpret_cast<float4*>(rout + base);
  op[0] = n0; op[1] = n1;

  float4* tp = reinterpret_cast<float4*>(tq + base);
  if (lvl == 0) {
    tp[0] = c0; tp[1] = c1;
  } else {
    float4 t0 = tp[0], t1 = tp[1];
    t0.x += c0.x; t0.y += c0.y; t0.z += c0.z; t0.w += c0.w;
    t1.x += c1.x; t1.y += c1.y; t1.z += c1.z; t1.w += c1.w;
    tp[0] = t0; tp[1] = t1;
  }

  float e = ((n0.x * n0.x + n0.y * n0.y) + (n0.z * n0.z + n0.w * n0.w)) +
            ((n1.x * n1.x + n1.y * n1.y) + (n1.z * n1.z + n1.w * n1.w));
  sred[tid] = e;
  __syncthreads();
  for (int s = 128; s > 0; s >>= 1) {
    if (tid < s) sred[tid] += sred[tid + s];
    __syncthreads();
  }
  if (tid == 0) part[blockIdx.x] = sred[0];
  if (tid < 8) fidx[blockIdx.x * 8 + tid] = (float)idx[blockIdx.x * 8 + tid];
}

// ---------------- loss finalize ----------------
__global__ __launch_bounds__(256) void k_loss(const float* __restrict__ part,
                                              float* __restrict__ out) {
  __shared__ float s[256];
  const int tid = threadIdx.x;
  float means[4];
  for (int l = 0; l < 4; ++l) {
    float sum = 0.f;
    for (int i = tid; i < 4096; i += 256) sum += part[l * 4096 + i];
    s[tid] = sum;
    __syncthreads();
    for (int st = 128; st > 0; st >>= 1) {
      if (tid < st) s[tid] += s[tid + st];
      __syncthreads();
    }
    means[l] = s[0] * (1.0f / 8388608.0f);  // /(N*D), exact pow2 scale
    __syncthreads();
  }
  if (tid == 0) {
    float t = ((means[0] + means[1]) + means[2]) + means[3];
    float loss = t * 0.25f;  // / L, exact
    out[0] = loss;
    out[1] = loss;
  }
}

// ---------------- straight-through estimator: out = x + (tq - x) ----------------
__global__ __launch_bounds__(256) void k_ste(const float* __restrict__ x,
                                             float* __restrict__ out, int n4) {
  int i = blockIdx.x * blockDim.x + threadIdx.x;
  if (i >= n4) return;
  float4 xv = reinterpret_cast<const float4*>(x)[i];
  float4 tv = reinterpret_cast<float4*>(out)[i];
  float4 o;
  o.x = xv.x + (tv.x - xv.x);
  o.y = xv.y + (tv.y - xv.y);
  o.z = xv.z + (tv.z - xv.z);
  o.w = xv.w + (tv.w - xv.w);
  reinterpret_cast<float4*>(out)[i] = o;
}

extern "C" void kernel_launch(void* const* d_in, const int* in_sizes, int n_in,
                              void* d_out, int out_size, void* d_ws, size_t ws_size,
                              hipStream_t stream) {
  const float* x  = (const float*)d_in[0];
  const float* cb = (const float*)d_in[1];
  float* out = (float*)d_out;
  float* ws  = (float*)d_ws;

  // ws layout (float units)
  float* res  = ws;                        // 8388608
  int*   idxw = (int*)(ws + 8388608);      // 32768 int32
  float* part = ws + 8388608 + 32768;      // 4*4096
  float* bv   = ws + 8388608 + 32768 + 16384;  // 4*1024

  float* tq      = out;                    // accumulate total_quant in d_out
  float* lossout = out + 8388608;
  float* fidx    = out + 8388610;

  k_bnorm<<<16, 256, 0, stream>>>(cb, bv);

  for (int l = 0; l < NLEV; ++l) {
    const float* rin = (l == 0) ? x : res;
    const float* cbl = cb + (size_t)l * KCODES * DIM;
    k_argmin<<<512, 256, 0, stream>>>(rin, cbl, bv + l * KCODES, idxw);
    k_update<<<4096, 256, 0, stream>>>(rin, res, cbl, idxw, tq,
                                       fidx + l * NROWS, part + l * 4096, l);
  }

  k_loss<<<1, 256, 0, stream>>>(part, lossout);
  k_ste<<<8192, 256, 0, stream>>>(x, out, 2097152);
}

// Round 2
// 1138.251 us; speedup vs baseline: 1.0313x; 1.0313x over previous
//
#include <hip/hip_runtime.h>

#define NROWS 32768   // B*T = 16*2048
#define DIM 256
#define KCODES 1024
#define NLEV 4

#define RT_LD 132     // stride % 32 == 4 -> <=2-way read conflicts, 4-way write (cheap)
#define CT_LD 260

// ---------------- codebook squared norms (all levels) ----------------
__global__ __launch_bounds__(256) void k_bnorm(const float* __restrict__ cb,
                                               float* __restrict__ bv) {
  int r = blockIdx.x * blockDim.x + threadIdx.x;  // 0..4095
  if (r >= NLEV * KCODES) return;
  const float4* p = reinterpret_cast<const float4*>(cb + (size_t)r * DIM);
  float s0 = 0.f, s1 = 0.f, s2 = 0.f, s3 = 0.f;
  for (int g = 0; g < DIM / 4; ++g) {
    float4 v = p[g];
    s0 += v.x * v.x; s1 += v.y * v.y; s2 += v.z * v.z; s3 += v.w * v.w;
  }
  bv[r] = (s0 + s1) + (s2 + s3);
}

// ---------------- fused distance + argmin, one level ----------------
// Block: 256 threads = 16 tx (codes) x 16 ty (rows). Block tile: 128 rows x 256 codes.
// Grid: 256 row-tiles x 4 code-quarters = 1024 blocks. Cross-quarter combine via
// u64 atomicMin of ((f32bits(dist)<<32)|code) -> lexicographic (d, idx) min.
// Distances bit-identical to the verified kernel: same per-(row,code) FMA chain
// over d ascending, same epilogue fl(fl(A+B) - 2*dot).
__global__ __launch_bounds__(256, 3) void k_argmin(const float* __restrict__ resid,
                                                   const float* __restrict__ cb,
                                                   const float* __restrict__ bv,
                                                   unsigned long long* __restrict__ best) {
  __shared__ __align__(16) float Rt[32][RT_LD];
  __shared__ __align__(16) float Ct[32][CT_LD];
  __shared__ float Asum[128];

  const int tid = threadIdx.x;
  const int tx = tid & 15;
  const int ty = tid >> 4;
  const int row0 = (blockIdx.x >> 2) * 128;
  const int cbase = (blockIdx.x & 3) * 256;

  // --- per-row ||r||^2 with the SAME association as the verified kernel:
  //     A = (P0+P1)+(P2+P3), each Pi a 64-elem float4-lane chain ---
  {
    int r = tid >> 1;      // 0..127
    int half = tid & 1;    // halves of 128 elems = two 64-elem chunks
    const float4* p = reinterpret_cast<const float4*>(
        resid + (size_t)(row0 + r) * DIM + half * 128);
    float s0 = 0.f, s1 = 0.f, s2 = 0.f, s3 = 0.f;
    #pragma unroll
    for (int g = 0; g < 16; ++g) {
      float4 v = p[g];
      s0 += v.x * v.x; s1 += v.y * v.y; s2 += v.z * v.z; s3 += v.w * v.w;
    }
    float pa = (s0 + s1) + (s2 + s3);
    s0 = 0.f; s1 = 0.f; s2 = 0.f; s3 = 0.f;
    #pragma unroll
    for (int g = 16; g < 32; ++g) {
      float4 v = p[g];
      s0 += v.x * v.x; s1 += v.y * v.y; s2 += v.z * v.z; s3 += v.w * v.w;
    }
    float pb = (s0 + s1) + (s2 + s3);
    float t = pa + pb;                 // half0: P0+P1, half1: P2+P3
    float o = __shfl_xor(t, 1);
    if (half == 0) Asum[r] = t + o;    // (P0+P1)+(P2+P3)
  }
  __syncthreads();

  float acc[8][16];
  #pragma unroll
  for (int i = 0; i < 8; ++i)
    #pragma unroll
    for (int j = 0; j < 16; ++j) acc[i][j] = 0.f;

  for (int d0 = 0; d0 < DIM; d0 += 32) {
    // stage R tile: 128 rows x 32 d, transposed into Rt[d][row]
    {
      int dd = (tid & 7) * 4;
      int rr = tid >> 3;  // 0..31
      #pragma unroll
      for (int pass = 0; pass < 4; ++pass) {
        float4 v = *reinterpret_cast<const float4*>(
            resid + (size_t)(row0 + rr) * DIM + d0 + dd);
        Rt[dd + 0][rr] = v.x; Rt[dd + 1][rr] = v.y;
        Rt[dd + 2][rr] = v.z; Rt[dd + 3][rr] = v.w;
        rr += 32;
      }
    }
    // stage C tile: 256 codes x 32 d, transposed into Ct[d][code]
    {
      int dd = (tid & 7) * 4;
      int cc = tid >> 3;  // 0..31
      #pragma unroll
      for (int pass = 0; pass < 8; ++pass) {
        float4 v = *reinterpret_cast<const float4*>(
            cb + (size_t)(cbase + cc) * DIM + d0 + dd);
        Ct[dd + 0][cc] = v.x; Ct[dd + 1][cc] = v.y;
        Ct[dd + 2][cc] = v.z; Ct[dd + 3][cc] = v.w;
        cc += 32;
      }
    }
    __syncthreads();
    #pragma unroll 2
    for (int d = 0; d < 32; ++d) {
      float4 r0 = *reinterpret_cast<const float4*>(&Rt[d][ty * 8]);
      float4 r1 = *reinterpret_cast<const float4*>(&Rt[d][ty * 8 + 4]);
      float4 c0 = *reinterpret_cast<const float4*>(&Ct[d][4 * tx]);
      float4 c1 = *reinterpret_cast<const float4*>(&Ct[d][64 + 4 * tx]);
      float4 c2 = *reinterpret_cast<const float4*>(&Ct[d][128 + 4 * tx]);
      float4 c3 = *reinterpret_cast<const float4*>(&Ct[d][192 + 4 * tx]);
      float rr8[8] = {r0.x, r0.y, r0.z, r0.w, r1.x, r1.y, r1.z, r1.w};
      float cc16[16] = {c0.x, c0.y, c0.z, c0.w, c1.x, c1.y, c1.z, c1.w,
                        c2.x, c2.y, c2.z, c2.w, c3.x, c3.y, c3.z, c3.w};
      #pragma unroll
      for (int i = 0; i < 8; ++i)
        #pragma unroll
        for (int j = 0; j < 16; ++j)
          acc[i][j] += rr8[i] * cc16[j];
    }
    __syncthreads();
  }

  // epilogue: quantized distances + running u64 (dist,idx) min; per-row
  // cross-tx shuffle reduce; one atomicMin per row per block.
  const float* bvq = bv + cbase;
  #pragma unroll
  for (int i = 0; i < 8; ++i) {
    const int row = row0 + ty * 8 + i;
    const float a = Asum[ty * 8 + i];
    unsigned long long u = ~0ull;
    #pragma unroll
    for (int j = 0; j < 4; ++j) {
      #pragma unroll
      for (int q = 0; q < 4; ++q) {
        int cl = 64 * j + 4 * tx + q;
        float t = a + bvq[cl];                    // fl(A + B)
        float dd = t - 2.0f * acc[i][4 * j + q];  // one rounding
        unsigned long long pk =
            ((unsigned long long)__float_as_uint(dd) << 32) |
            (unsigned)(cbase + cl);
        u = (pk < u) ? pk : u;
      }
    }
    #pragma unroll
    for (int m = 1; m < 16; m <<= 1) {
      unsigned long long o = __shfl_xor(u, m);
      u = (o < u) ? o : u;
    }
    if (tx == 0) atomicMin(best + row, u);
  }
}

// ---------------- residual update + quant accumulate + loss partials ----------------
// block: 256 threads, 8 rows/block; lvl 3 also applies the STE epilogue.
__global__ __launch_bounds__(256) void k_update(const float* __restrict__ rin,
                                                float* __restrict__ rout,
                                                const float* __restrict__ cb,
                                                const unsigned long long* __restrict__ best,
                                                float* __restrict__ tq,
                                                float* __restrict__ fidx,
                                                float* __restrict__ part,
                                                const float* __restrict__ x,
                                                int lvl) {
  __shared__ float sred[256];
  const int tid = threadIdx.x;
  const int row = blockIdx.x * 8 + (tid >> 5);
  const int lane = tid & 31;
  const int id = (int)(best[row] & 0xffffffffull);
  const size_t base = (size_t)row * DIM + lane * 8;

  const float4* rp = reinterpret_cast<const float4*>(rin + base);
  const float4* cp = reinterpret_cast<const float4*>(cb + (size_t)id * DIM + lane * 8);
  float4 r0 = rp[0], r1 = rp[1];
  float4 c0 = cp[0], c1 = cp[1];
  float4 n0, n1;
  n0.x = r0.x - c0.x; n0.y = r0.y - c0.y; n0.z = r0.z - c0.z; n0.w = r0.w - c0.w;
  n1.x = r1.x - c1.x; n1.y = r1.y - c1.y; n1.z = r1.z - c1.z; n1.w = r1.w - c1.w;
  float4* op = reinterpret_cast<float4*>(rout + base);
  op[0] = n0; op[1] = n1;

  float4* tp = reinterpret_cast<float4*>(tq + base);
  if (lvl == 0) {
    tp[0] = c0; tp[1] = c1;
  } else {
    float4 t0 = tp[0], t1 = tp[1];
    t0.x += c0.x; t0.y += c0.y; t0.z += c0.z; t0.w += c0.w;
    t1.x += c1.x; t1.y += c1.y; t1.z += c1.z; t1.w += c1.w;
    if (lvl == 3) {
      // STE: out = x + (total_quant - x)
      const float4* xp = reinterpret_cast<const float4*>(x + base);
      float4 x0 = xp[0], x1 = xp[1];
      t0.x = x0.x + (t0.x - x0.x); t0.y = x0.y + (t0.y - x0.y);
      t0.z = x0.z + (t0.z - x0.z); t0.w = x0.w + (t0.w - x0.w);
      t1.x = x1.x + (t1.x - x1.x); t1.y = x1.y + (t1.y - x1.y);
      t1.z = x1.z + (t1.z - x1.z); t1.w = x1.w + (t1.w - x1.w);
    }
    tp[0] = t0; tp[1] = t1;
  }

  float e = ((n0.x * n0.x + n0.y * n0.y) + (n0.z * n0.z + n0.w * n0.w)) +
            ((n1.x * n1.x + n1.y * n1.y) + (n1.z * n1.z + n1.w * n1.w));
  sred[tid] = e;
  __syncthreads();
  for (int s = 128; s > 0; s >>= 1) {
    if (tid < s) sred[tid] += sred[tid + s];
    __syncthreads();
  }
  if (tid == 0) part[blockIdx.x] = sred[0];
  if ((tid & 31) == 0) fidx[row] = (float)id;
}

// ---------------- loss finalize ----------------
__global__ __launch_bounds__(256) void k_loss(const float* __restrict__ part,
                                              float* __restrict__ out) {
  __shared__ float s[256];
  const int tid = threadIdx.x;
  float means[4];
  for (int l = 0; l < 4; ++l) {
    float sum = 0.f;
    for (int i = tid; i < 4096; i += 256) sum += part[l * 4096 + i];
    s[tid] = sum;
    __syncthreads();
    for (int st = 128; st > 0; st >>= 1) {
      if (tid < st) s[tid] += s[tid + st];
      __syncthreads();
    }
    means[l] = s[0] * (1.0f / 8388608.0f);  // /(N*D), exact pow2 scale
    __syncthreads();
  }
  if (tid == 0) {
    float t = ((means[0] + means[1]) + means[2]) + means[3];
    float loss = t * 0.25f;  // / L, exact
    out[0] = loss;
    out[1] = loss;
  }
}

extern "C" void kernel_launch(void* const* d_in, const int* in_sizes, int n_in,
                              void* d_out, int out_size, void* d_ws, size_t ws_size,
                              hipStream_t stream) {
  const float* x  = (const float*)d_in[0];
  const float* cb = (const float*)d_in[1];
  float* out = (float*)d_out;
  float* ws  = (float*)d_ws;

  // ws layout (float units)
  float* res = ws;                                             // 8388608
  unsigned long long* best4 = (unsigned long long*)(ws + 8388608);  // 4*32768 u64
  float* part = ws + 8388608 + 262144;                         // 4*4096
  float* bv   = ws + 8388608 + 262144 + 16384;                 // 4*1024

  float* tq      = out;                    // total_quant accumulates in d_out
  float* lossout = out + 8388608;
  float* fidx    = out + 8388610;

  hipMemsetAsync(best4, 0xFF, (size_t)NLEV * NROWS * 8, stream);
  k_bnorm<<<16, 256, 0, stream>>>(cb, bv);

  for (int l = 0; l < NLEV; ++l) {
    const float* rin = (l == 0) ? x : res;
    const float* cbl = cb + (size_t)l * KCODES * DIM;
    k_argmin<<<1024, 256, 0, stream>>>(rin, cbl, bv + l * KCODES,
                                       best4 + (size_t)l * NROWS);
    k_update<<<4096, 256, 0, stream>>>(rin, res, cbl, best4 + (size_t)l * NROWS,
                                       tq, fidx + (size_t)l * NROWS,
                                       part + l * 4096, x, l);
  }

  k_loss<<<1, 256, 0, stream>>>(part, lossout);
}